// Round 9
// baseline (463.523 us; speedup 1.0000x reference)
//
#include <hip/hip_runtime.h>

// ConeIntersection fused kernel for MI355X (gfx950).
// N=4, B=8192, DIM=1024, HEADS=4, HD=256. Device buffers FP32; comparison in
// bf16 domain (2% of max). Numerics byte-identical to passing r3/r8 kernels
// (2-term f16 RNE splits, 3 MFMAs/product axis path; plain f16 arg path;
// pre-scaled x16, scores /256).
//
// Round-9:
//  - split_inputs prep kernel DELETED: staging loads fp32 and splits in
//    registers (same split16), writes hi/lo to LDS. ~70us prep was pure
//    overhead (split arrays were read exactly once).
//  - GEMM1's two loops merged at kk granularity: 8 ds_reads + 12 weight
//    loads feed 32 independent MFMAs per iteration (2x per-iter ILP).
//  - s_setprio(1/0) around MFMA clusters.
//  - Keeps: r8 A-tile LDS staging w/ XOR swizzle, fragment-linear weights,
//    reg-pipelined GEMM2, 8 pairs/block, XCD-swizzled grid 4096.

typedef __attribute__((ext_vector_type(8))) _Float16 f16x8;
typedef __attribute__((ext_vector_type(8))) float f32x8;
typedef __attribute__((ext_vector_type(4))) float f32x4;

#define BH 32768            // B*HEADS pairs
#define OUT_ARG_OFF 8388608 // B*DIM

// ws layout in halfs (fragment-linear within each array)
#define O_WXA_H 0
#define O_WXA_L 65536
#define O_WXR_H 131072
#define O_WXR_L 196608
#define O_WRA_H 262144
#define O_WRR_H 327680
#define O_W2X_H 393216
#define O_W2X_L 458752
#define O_W2G_H 524288
#define WS_HALFS 589824     // 1179648 bytes

__device__ __forceinline__ void split16(float x, _Float16& hi, _Float16& lo) {
  float xs = x * 16.0f;
  _Float16 h = (_Float16)xs;      // RNE
  hi = h;
  lo = (_Float16)(xs - (float)h); // residual; product error ~2^-22
}

// fragment-linear index for weights: element (col o, k) -> tile (o>>4, k>>5),
// lane ((k>>3)&3)*16 + (o&15), slot j=k&7.
__device__ __forceinline__ int fragidx(int o, int k) {
  int ct = o >> 4, kk = k >> 5, lg = (k >> 3) & 3, l15 = o & 15, j = k & 7;
  return (ct * 8 + kk) * 512 + (lg * 16 + l15) * 8 + j;
}

// ---- prep: combined + split layer weights (x16-scaled, frag-linear) ----
__global__ void combine_weights(const float* __restrict__ Wx1, const float* __restrict__ Wr1,
                                const float* __restrict__ W2x, const float* __restrict__ W2g,
                                _Float16* __restrict__ ws) {
  int i = blockIdx.x * 256 + threadIdx.x;  // 0..65535 ; o=i>>8, k=i&255
  int o = i >> 8, k = i & 255;
  int d = fragidx(o, k);
  float a = Wx1[o * 512 + k], b = Wx1[o * 512 + 256 + k];
  _Float16 h, l;
  split16(a + b, h, l);          ws[O_WXA_H + d] = h; ws[O_WXA_L + d] = l;
  split16(0.5f * (b - a), h, l); ws[O_WXR_H + d] = h; ws[O_WXR_L + d] = l;
  a = Wr1[o * 512 + k]; b = Wr1[o * 512 + 256 + k];
  ws[O_WRA_H + d] = (_Float16)((a + b) * 16.0f);
  ws[O_WRR_H + d] = (_Float16)((0.5f * (b - a)) * 16.0f);
  split16(W2x[o * 256 + k], h, l); ws[O_W2X_H + d] = h; ws[O_W2X_L + d] = l;
  ws[O_W2G_H + d] = (_Float16)(W2g[o * 256 + k] * 16.0f);
}

#define MFMA16 __builtin_amdgcn_mfma_f32_16x16x32_f16

__global__ __launch_bounds__(512, 4)
void cone_main(const float* __restrict__ axisF, const float* __restrict__ argF,
               const float* __restrict__ bx1, const float* __restrict__ br1,
               const float* __restrict__ bg2,
               const _Float16* __restrict__ ws, float* __restrict__ out)
{
  __shared__ __align__(16) _Float16 lds[32768];  // 64KB
  _Float16* bufAxH = lds;            // 32x256 axis hi  -> later h1h
  _Float16* bufAxL = lds + 8192;     // 32x256 axis lo  -> later h1l
  _Float16* bufArH = lds + 16384;    // 32x256 arg hi   -> later h1m (16x256)
  _Float16* bufArL = lds + 24576;    // 32x256 arg lo

  const int tid = threadIdx.x;
  const int w   = tid >> 6;
  const int l   = tid & 63;
  const int l15 = l & 15;
  const int lg  = l >> 4;
  int bid = blockIdx.x;
  bid = ((bid & 7) << 9) + (bid >> 3);   // XCD swizzle (4096 % 8 == 0)
  const int g0 = bid << 3;               // 8 pairs/block
  const float s = 1.0f / 256.0f;

  // ---------- stage A tiles: fp32 global -> reg split16 -> swizzled LDS ----
  {
    #pragma unroll
    for (int c = 0; c < 2; ++c) {
      const int i   = c * 512 + tid;
      const int row = i >> 5;            // 0..31 : pair = row>>2... no: n = row&3, pair = row>>2
      const int col = (i & 31) * 8;      // halfs / floats
      const int gofs = ((row & 3) * BH + g0 + (row >> 2)) * 256 + col;
      f32x8 va = *(const f32x8*)(axisF + gofs);
      f32x8 vr = *(const f32x8*)(argF + gofs);
      f16x8 xh, xl, rh, rl;
      #pragma unroll
      for (int j = 0; j < 8; ++j) {
        _Float16 h, lo2;
        split16(va[j], h, lo2); xh[j] = h; xl[j] = lo2;
        split16(vr[j], h, lo2); rh[j] = h; rl[j] = lo2;
      }
      const int ad = row * 256 + (col ^ ((row & 7) << 3));
      *(f16x8*)(bufAxH + ad) = xh;
      *(f16x8*)(bufAxL + ad) = xl;
      *(f16x8*)(bufArH + ad) = rh;
      *(f16x8*)(bufArL + ad) = rl;
    }
  }
  __syncthreads();

  // ---------- GEMM1 merged: both operands per kk, 32 MFMAs/iter ----------
  f32x4 acc1[2][2], accm[2][2];   // [mt][nt]
  #pragma unroll
  for (int mt = 0; mt < 2; ++mt)
    #pragma unroll
    for (int nt = 0; nt < 2; ++nt) { acc1[mt][nt] = (f32x4){0,0,0,0}; accm[mt][nt] = (f32x4){0,0,0,0}; }

  const int ct0 = w << 1;  // this wave's first col-tile (nt adds 0/1)

  #pragma unroll
  for (int kk = 0; kk < 8; ++kk) {
    f16x8 xh[2], xl[2], rh[2], rl[2];
    #pragma unroll
    for (int mt = 0; mt < 2; ++mt) {
      const int row = (mt << 4) + l15;
      const int ad  = row * 256 + ((((kk) << 5) + (lg << 3)) ^ ((row & 7) << 3));
      xh[mt] = *(const f16x8*)(bufAxH + ad);
      xl[mt] = *(const f16x8*)(bufAxL + ad);
      rh[mt] = *(const f16x8*)(bufArH + ad);
      rl[mt] = *(const f16x8*)(bufArL + ad);
    }
    #pragma unroll
    for (int nt = 0; nt < 2; ++nt) {
      const int fb = (((ct0 + nt) << 3) + kk) * 512 + l * 8;
      const f16x8 wxah = *(const f16x8*)(ws + O_WXA_H + fb);
      const f16x8 wxal = *(const f16x8*)(ws + O_WXA_L + fb);
      const f16x8 wraw = *(const f16x8*)(ws + O_WRA_H + fb);
      const f16x8 wxrh = *(const f16x8*)(ws + O_WXR_H + fb);
      const f16x8 wxrl = *(const f16x8*)(ws + O_WXR_L + fb);
      const f16x8 wrrw = *(const f16x8*)(ws + O_WRR_H + fb);
      __builtin_amdgcn_s_setprio(1);
      #pragma unroll
      for (int mt = 0; mt < 2; ++mt) {
        acc1[mt][nt] = MFMA16(xh[mt], wxah, acc1[mt][nt], 0, 0, 0);
        acc1[mt][nt] = MFMA16(xl[mt], wxah, acc1[mt][nt], 0, 0, 0);
        acc1[mt][nt] = MFMA16(xh[mt], wxal, acc1[mt][nt], 0, 0, 0);
        accm[mt][nt] = MFMA16(xh[mt], wraw, accm[mt][nt], 0, 0, 0);
        acc1[mt][nt] = MFMA16(rh[mt], wxrh, acc1[mt][nt], 0, 0, 0);
        acc1[mt][nt] = MFMA16(rl[mt], wxrh, acc1[mt][nt], 0, 0, 0);
        acc1[mt][nt] = MFMA16(rh[mt], wxrl, acc1[mt][nt], 0, 0, 0);
        accm[mt][nt] = MFMA16(rh[mt], wrrw, accm[mt][nt], 0, 0, 0);
      }
      __builtin_amdgcn_s_setprio(0);
    }
  }
  __syncthreads();   // all waves done reading bufAx/bufAr

  // ---------- epilogue 1: h1 (split) -> LDS overlay; h1m mean -> LDS ----
  _Float16* h1h = bufAxH;   // 32x256
  _Float16* h1l = bufAxL;   // 32x256
  _Float16* h1m = bufArH;   // 16x256 (rows 8..15 zeroed)
  if (tid < 256) *(f16x8*)(h1m + 2048 + tid * 8) = (f16x8){0,0,0,0,0,0,0,0};
  #pragma unroll
  for (int nt = 0; nt < 2; ++nt) {
    const int c  = (w << 5) + (nt << 4) + l15;
    const float bvx = bx1[c];
    const float bvr = br1[c];
    #pragma unroll
    for (int mt = 0; mt < 2; ++mt) {
      #pragma unroll
      for (int r = 0; r < 4; ++r) {
        const int row = (mt << 4) + (lg << 2) + r;
        const float v = fmaxf(acc1[mt][nt][r] * s + bvx, 0.f);
        _Float16 h, lo2; split16(v, h, lo2);
        const int ad = row * 256 + (c ^ ((row & 7) << 3));
        h1h[ad] = h; h1l[ad] = lo2;
      }
      const int p = (mt << 2) + lg;   // pair index 0..7
      float sm = 0.f;
      #pragma unroll
      for (int r = 0; r < 4; ++r) sm += fmaxf(accm[mt][nt][r] * s + bvr, 0.f);
      h1m[p * 256 + (c ^ ((p & 7) << 3))] = (_Float16)(0.25f * sm * 16.0f);
    }
  }
  __syncthreads();

  // ---------- GEMM2 (attn logits, split) + gate (plain) ----------
  f32x4 acc2[2][2];
  f32x4 acc3[2];
  #pragma unroll
  for (int mt = 0; mt < 2; ++mt) { acc2[mt][0] = (f32x4){0,0,0,0}; acc2[mt][1] = (f32x4){0,0,0,0}; }
  acc3[0] = (f32x4){0,0,0,0}; acc3[1] = (f32x4){0,0,0,0};
  {
    f16x8 wh[3][2], wl[3][2], wg[3][2];
    f16x8 a2h[2][2], a2l[2][2], am[2];
    #pragma unroll
    for (int p = 0; p < 2; ++p)
      #pragma unroll
      for (int nt = 0; nt < 2; ++nt) {
        const int fb = (((ct0 + nt) << 3) + p) * 512 + l * 8;
        wh[p][nt] = *(const f16x8*)(ws + O_W2X_H + fb);
        wl[p][nt] = *(const f16x8*)(ws + O_W2X_L + fb);
        wg[p][nt] = *(const f16x8*)(ws + O_W2G_H + fb);
      }
    #pragma unroll
    for (int mt = 0; mt < 2; ++mt) {
      const int row = (mt << 4) + l15;
      const int ad  = row * 256 + ((lg << 3) ^ ((row & 7) << 3));
      a2h[0][mt] = *(const f16x8*)(h1h + ad);
      a2l[0][mt] = *(const f16x8*)(h1l + ad);
    }
    am[0] = *(const f16x8*)(h1m + l15 * 256 + ((lg << 3) ^ ((l15 & 7) << 3)));
    #pragma unroll
    for (int kk = 0; kk < 8; ++kk) {
      const int cs = kk % 3, ns = (kk + 2) % 3, ab = kk & 1, an = ab ^ 1;
      if (kk < 6) {
        #pragma unroll
        for (int nt = 0; nt < 2; ++nt) {
          const int fb = (((ct0 + nt) << 3) + (kk + 2)) * 512 + l * 8;
          wh[ns][nt] = *(const f16x8*)(ws + O_W2X_H + fb);
          wl[ns][nt] = *(const f16x8*)(ws + O_W2X_L + fb);
          wg[ns][nt] = *(const f16x8*)(ws + O_W2G_H + fb);
        }
      }
      if (kk < 7) {
        #pragma unroll
        for (int mt = 0; mt < 2; ++mt) {
          const int row = (mt << 4) + l15;
          const int ad  = row * 256 + ((((kk + 1) << 5) + (lg << 3)) ^ ((row & 7) << 3));
          a2h[an][mt] = *(const f16x8*)(h1h + ad);
          a2l[an][mt] = *(const f16x8*)(h1l + ad);
        }
        am[an] = *(const f16x8*)(h1m + l15 * 256 + ((((kk + 1) << 5) + (lg << 3)) ^ ((l15 & 7) << 3)));
      }
      __builtin_amdgcn_s_setprio(1);
      #pragma unroll
      for (int nt = 0; nt < 2; ++nt) {
        #pragma unroll
        for (int mt = 0; mt < 2; ++mt) {
          acc2[mt][nt] = MFMA16(a2h[ab][mt], wh[cs][nt], acc2[mt][nt], 0, 0, 0);
          acc2[mt][nt] = MFMA16(a2l[ab][mt], wh[cs][nt], acc2[mt][nt], 0, 0, 0);
          acc2[mt][nt] = MFMA16(a2h[ab][mt], wl[cs][nt], acc2[mt][nt], 0, 0, 0);
        }
        acc3[nt] = MFMA16(am[ab], wg[cs][nt], acc3[nt], 0, 0, 0);
      }
      __builtin_amdgcn_s_setprio(0);
    }
  }

  // ---- softmax over n (in-lane) + circular mean -> axis_out (fp32) ----
  // b_axis2 omitted: constant per column across n, cancels in softmax(axis=0).
  #pragma unroll
  for (int nt = 0; nt < 2; ++nt) {
    const int c = (w << 5) + (nt << 4) + l15;
    #pragma unroll
    for (int mt = 0; mt < 2; ++mt) {
      float lv[4];
      #pragma unroll
      for (int r = 0; r < 4; ++r) lv[r] = acc2[mt][nt][r] * s;
      const float mx = fmaxf(fmaxf(lv[0], lv[1]), fmaxf(lv[2], lv[3]));
      float e[4]; float sum = 0.f;
      #pragma unroll
      for (int r = 0; r < 4; ++r) { e[r] = __expf(lv[r] - mx); sum += e[r]; }
      const float inv = 1.f / sum;
      const int g = g0 + (mt << 2) + lg;
      float x = 0.f, y = 0.f;
      #pragma unroll
      for (int r = 0; r < 4; ++r) {
        const float av = axisF[(r * BH + g) * 256 + c];
        float sn, cs2;
        __sincosf(av, &sn, &cs2);
        const float at = e[r] * inv;
        x += at * cs2;
        y += at * sn;
      }
      if (fabsf(x) < 0.001f) x = 0.001f;
      out[g * 256 + c] = atan2f(y, x);
    }
  }

  // ---- sigmoid gate * min_n arg -> arg_out (fp32) ----
  #pragma unroll
  for (int nt = 0; nt < 2; ++nt) {
    const int c = (w << 5) + (nt << 4) + l15;
    const float bgv = bg2[c];
    #pragma unroll
    for (int r = 0; r < 4; ++r) {
      const int p = (lg << 2) + r;   // gate C row = pair index; only 0..7 live
      if (p < 8) {
        const int g = g0 + p;
        const float gate = 1.f / (1.f + __expf(-(acc3[nt][r] * s + bgv)));
        float mn = argF[g * 256 + c];
        #pragma unroll
        for (int n = 1; n < 4; ++n)
          mn = fminf(mn, argF[(n * BH + g) * 256 + c]);
        out[OUT_ARG_OFF + g * 256 + c] = mn * gate;
      }
    }
  }
}

extern "C" void kernel_launch(void* const* d_in, const int* in_sizes, int n_in,
                              void* d_out, int out_size, void* d_ws, size_t ws_size,
                              hipStream_t stream) {
  const float* axisF = (const float*)d_in[0];
  const float* argF  = (const float*)d_in[1];
  const float* Wx1   = (const float*)d_in[2];
  const float* bx1   = (const float*)d_in[3];
  const float* Wr1   = (const float*)d_in[4];
  const float* br1   = (const float*)d_in[5];
  const float* W2x   = (const float*)d_in[6];
  // d_in[7] = b_axis2: constant over n at fixed column -> cancels in softmax
  const float* W2g   = (const float*)d_in[8];
  const float* bg2   = (const float*)d_in[9];
  float* out = (float*)d_out;
  _Float16* ws = (_Float16*)d_ws;

  combine_weights<<<256, 256, 0, stream>>>(Wx1, Wr1, W2x, W2g, ws);
  cone_main<<<4096, 512, 0, stream>>>(axisF, argF, bx1, br1, bg2, ws, out);
}

// Round 10
// 302.667 us; speedup vs baseline: 1.5315x; 1.5315x over previous
//
#include <hip/hip_runtime.h>

// ConeIntersection fused kernel for MI355X (gfx950).
// N=4, B=8192, DIM=1024, HEADS=4, HD=256. Device buffers FP32; comparison in
// bf16 domain (2% of max). Numerics byte-identical to passing r3/r8/r9 kernels
// (2-term f16 RNE splits, 3 MFMAs/product axis path; plain f16 arg path;
// pre-scaled x16, scores /256).
//
// Round-10 = r8 structure + r9's fused staging (controlled A/B vs r9):
//  - Staging loads fp32, split16 in registers, writes hi/lo to swizzled LDS
//    (split_inputs prep kernel stays deleted: -70us, proven in r9).
//  - GEMM1 back to TWO separate loops (axis-operand, arg-operand) with
//    3-buffer software-pipelined weights — r9's merged loop SPILLED
//    (WRITE_SIZE 76->731MB, +95us). No setprio (isolate variables).
//  - launch_bounds(512,2), 8 pairs/block, XCD-swizzled grid 4096,
//    fragment-linear weights in d_ws.

typedef __attribute__((ext_vector_type(8))) _Float16 f16x8;
typedef __attribute__((ext_vector_type(8))) float f32x8;
typedef __attribute__((ext_vector_type(4))) float f32x4;

#define BH 32768            // B*HEADS pairs
#define OUT_ARG_OFF 8388608 // B*DIM

// ws layout in halfs (fragment-linear within each array)
#define O_WXA_H 0
#define O_WXA_L 65536
#define O_WXR_H 131072
#define O_WXR_L 196608
#define O_WRA_H 262144
#define O_WRR_H 327680
#define O_W2X_H 393216
#define O_W2X_L 458752
#define O_W2G_H 524288
#define WS_HALFS 589824     // 1179648 bytes

__device__ __forceinline__ void split16(float x, _Float16& hi, _Float16& lo) {
  float xs = x * 16.0f;
  _Float16 h = (_Float16)xs;      // RNE
  hi = h;
  lo = (_Float16)(xs - (float)h); // residual; product error ~2^-22
}

// fragment-linear index for weights: element (col o, k) -> tile (o>>4, k>>5),
// lane ((k>>3)&3)*16 + (o&15), slot j=k&7.
__device__ __forceinline__ int fragidx(int o, int k) {
  int ct = o >> 4, kk = k >> 5, lg = (k >> 3) & 3, l15 = o & 15, j = k & 7;
  return (ct * 8 + kk) * 512 + (lg * 16 + l15) * 8 + j;
}

// ---- prep: combined + split layer weights (x16-scaled, frag-linear) ----
__global__ void combine_weights(const float* __restrict__ Wx1, const float* __restrict__ Wr1,
                                const float* __restrict__ W2x, const float* __restrict__ W2g,
                                _Float16* __restrict__ ws) {
  int i = blockIdx.x * 256 + threadIdx.x;  // 0..65535 ; o=i>>8, k=i&255
  int o = i >> 8, k = i & 255;
  int d = fragidx(o, k);
  float a = Wx1[o * 512 + k], b = Wx1[o * 512 + 256 + k];
  _Float16 h, l;
  split16(a + b, h, l);          ws[O_WXA_H + d] = h; ws[O_WXA_L + d] = l;
  split16(0.5f * (b - a), h, l); ws[O_WXR_H + d] = h; ws[O_WXR_L + d] = l;
  a = Wr1[o * 512 + k]; b = Wr1[o * 512 + 256 + k];
  ws[O_WRA_H + d] = (_Float16)((a + b) * 16.0f);
  ws[O_WRR_H + d] = (_Float16)((0.5f * (b - a)) * 16.0f);
  split16(W2x[o * 256 + k], h, l); ws[O_W2X_H + d] = h; ws[O_W2X_L + d] = l;
  ws[O_W2G_H + d] = (_Float16)(W2g[o * 256 + k] * 16.0f);
}

#define MFMA16 __builtin_amdgcn_mfma_f32_16x16x32_f16

__global__ __launch_bounds__(512, 2)
void cone_main(const float* __restrict__ axisF, const float* __restrict__ argF,
               const float* __restrict__ bx1, const float* __restrict__ br1,
               const float* __restrict__ bg2,
               const _Float16* __restrict__ ws, float* __restrict__ out)
{
  __shared__ __align__(16) _Float16 lds[32768];  // 64KB
  _Float16* bufAxH = lds;            // 32x256 axis hi  -> later h1h
  _Float16* bufAxL = lds + 8192;     // 32x256 axis lo  -> later h1l
  _Float16* bufArH = lds + 16384;    // 32x256 arg hi   -> later h1m (16x256)
  _Float16* bufArL = lds + 24576;    // 32x256 arg lo

  const int tid = threadIdx.x;
  const int w   = tid >> 6;
  const int l   = tid & 63;
  const int l15 = l & 15;
  const int lg  = l >> 4;
  int bid = blockIdx.x;
  bid = ((bid & 7) << 9) + (bid >> 3);   // XCD swizzle (4096 % 8 == 0)
  const int g0 = bid << 3;               // 8 pairs/block
  const float s = 1.0f / 256.0f;

  // ---------- stage A tiles: fp32 global -> reg split16 -> swizzled LDS ----
  {
    #pragma unroll
    for (int c = 0; c < 2; ++c) {
      const int i   = c * 512 + tid;
      const int row = i >> 5;            // 0..31 ; n = row&3, pair = row>>2
      const int col = (i & 31) * 8;      // halfs / floats
      const int gofs = ((row & 3) * BH + g0 + (row >> 2)) * 256 + col;
      f32x8 va = *(const f32x8*)(axisF + gofs);
      f32x8 vr = *(const f32x8*)(argF + gofs);
      f16x8 xh, xl, rh, rl;
      #pragma unroll
      for (int j = 0; j < 8; ++j) {
        _Float16 h, lo2;
        split16(va[j], h, lo2); xh[j] = h; xl[j] = lo2;
        split16(vr[j], h, lo2); rh[j] = h; rl[j] = lo2;
      }
      const int ad = row * 256 + (col ^ ((row & 7) << 3));
      *(f16x8*)(bufAxH + ad) = xh;
      *(f16x8*)(bufAxL + ad) = xl;
      *(f16x8*)(bufArH + ad) = rh;
      *(f16x8*)(bufArL + ad) = rl;
    }
  }
  __syncthreads();

  // accumulators persist across both operand loops
  f32x4 acc1[2][2], accm[2][2];   // [mt][nt]
  #pragma unroll
  for (int mt = 0; mt < 2; ++mt)
    #pragma unroll
    for (int nt = 0; nt < 2; ++nt) { acc1[mt][nt] = (f32x4){0,0,0,0}; accm[mt][nt] = (f32x4){0,0,0,0}; }

  const int ct0 = w << 1;  // this wave's first col-tile (nt adds 0/1)

  // ---------- loop 0: operand = axis (hi/lo in LDS); W = WXA h/l, WRA ----
  {
    f16x8 wh[3][2], wl[3][2], wm[3][2];
    f16x8 ah[2][2], al[2][2];
    #pragma unroll
    for (int p = 0; p < 2; ++p)
      #pragma unroll
      for (int nt = 0; nt < 2; ++nt) {
        const int fb = (((ct0 + nt) << 3) + p) * 512 + l * 8;
        wh[p][nt] = *(const f16x8*)(ws + O_WXA_H + fb);
        wl[p][nt] = *(const f16x8*)(ws + O_WXA_L + fb);
        wm[p][nt] = *(const f16x8*)(ws + O_WRA_H + fb);
      }
    #pragma unroll
    for (int mt = 0; mt < 2; ++mt) {
      const int row = (mt << 4) + l15;
      const int ad  = row * 256 + ((lg << 3) ^ ((row & 7) << 3));
      ah[0][mt] = *(const f16x8*)(bufAxH + ad);
      al[0][mt] = *(const f16x8*)(bufAxL + ad);
    }
    #pragma unroll
    for (int kk = 0; kk < 8; ++kk) {
      const int cs = kk % 3, ns = (kk + 2) % 3, ab = kk & 1, an = ab ^ 1;
      if (kk < 6) {
        #pragma unroll
        for (int nt = 0; nt < 2; ++nt) {
          const int fb = (((ct0 + nt) << 3) + (kk + 2)) * 512 + l * 8;
          wh[ns][nt] = *(const f16x8*)(ws + O_WXA_H + fb);
          wl[ns][nt] = *(const f16x8*)(ws + O_WXA_L + fb);
          wm[ns][nt] = *(const f16x8*)(ws + O_WRA_H + fb);
        }
      }
      if (kk < 7) {
        #pragma unroll
        for (int mt = 0; mt < 2; ++mt) {
          const int row = (mt << 4) + l15;
          const int ad  = row * 256 + ((((kk + 1) << 5) + (lg << 3)) ^ ((row & 7) << 3));
          ah[an][mt] = *(const f16x8*)(bufAxH + ad);
          al[an][mt] = *(const f16x8*)(bufAxL + ad);
        }
      }
      #pragma unroll
      for (int nt = 0; nt < 2; ++nt)
        #pragma unroll
        for (int mt = 0; mt < 2; ++mt) {
          acc1[mt][nt] = MFMA16(ah[ab][mt], wh[cs][nt], acc1[mt][nt], 0, 0, 0);
          acc1[mt][nt] = MFMA16(al[ab][mt], wh[cs][nt], acc1[mt][nt], 0, 0, 0);
          acc1[mt][nt] = MFMA16(ah[ab][mt], wl[cs][nt], acc1[mt][nt], 0, 0, 0);
          accm[mt][nt] = MFMA16(ah[ab][mt], wm[cs][nt], accm[mt][nt], 0, 0, 0);
        }
    }
  }

  // ---------- loop 1: operand = arg (hi/lo in LDS); W = WXR h/l, WRR ----
  {
    f16x8 wh[3][2], wl[3][2], wm[3][2];
    f16x8 ah[2][2], al[2][2];
    #pragma unroll
    for (int p = 0; p < 2; ++p)
      #pragma unroll
      for (int nt = 0; nt < 2; ++nt) {
        const int fb = (((ct0 + nt) << 3) + p) * 512 + l * 8;
        wh[p][nt] = *(const f16x8*)(ws + O_WXR_H + fb);
        wl[p][nt] = *(const f16x8*)(ws + O_WXR_L + fb);
        wm[p][nt] = *(const f16x8*)(ws + O_WRR_H + fb);
      }
    #pragma unroll
    for (int mt = 0; mt < 2; ++mt) {
      const int row = (mt << 4) + l15;
      const int ad  = row * 256 + ((lg << 3) ^ ((row & 7) << 3));
      ah[0][mt] = *(const f16x8*)(bufArH + ad);
      al[0][mt] = *(const f16x8*)(bufArL + ad);
    }
    #pragma unroll
    for (int kk = 0; kk < 8; ++kk) {
      const int cs = kk % 3, ns = (kk + 2) % 3, ab = kk & 1, an = ab ^ 1;
      if (kk < 6) {
        #pragma unroll
        for (int nt = 0; nt < 2; ++nt) {
          const int fb = (((ct0 + nt) << 3) + (kk + 2)) * 512 + l * 8;
          wh[ns][nt] = *(const f16x8*)(ws + O_WXR_H + fb);
          wl[ns][nt] = *(const f16x8*)(ws + O_WXR_L + fb);
          wm[ns][nt] = *(const f16x8*)(ws + O_WRR_H + fb);
        }
      }
      if (kk < 7) {
        #pragma unroll
        for (int mt = 0; mt < 2; ++mt) {
          const int row = (mt << 4) + l15;
          const int ad  = row * 256 + ((((kk + 1) << 5) + (lg << 3)) ^ ((row & 7) << 3));
          ah[an][mt] = *(const f16x8*)(bufArH + ad);
          al[an][mt] = *(const f16x8*)(bufArL + ad);
        }
      }
      #pragma unroll
      for (int nt = 0; nt < 2; ++nt)
        #pragma unroll
        for (int mt = 0; mt < 2; ++mt) {
          acc1[mt][nt] = MFMA16(ah[ab][mt], wh[cs][nt], acc1[mt][nt], 0, 0, 0);
          acc1[mt][nt] = MFMA16(al[ab][mt], wh[cs][nt], acc1[mt][nt], 0, 0, 0);
          acc1[mt][nt] = MFMA16(ah[ab][mt], wl[cs][nt], acc1[mt][nt], 0, 0, 0);
          accm[mt][nt] = MFMA16(ah[ab][mt], wm[cs][nt], accm[mt][nt], 0, 0, 0);
        }
    }
  }
  __syncthreads();   // all waves done reading bufAx/bufAr

  // ---------- epilogue 1: h1 (split) -> LDS overlay; h1m mean -> LDS ----
  _Float16* h1h = bufAxH;   // 32x256
  _Float16* h1l = bufAxL;   // 32x256
  _Float16* h1m = bufArH;   // 16x256 (rows 8..15 zeroed)
  if (tid < 256) *(f16x8*)(h1m + 2048 + tid * 8) = (f16x8){0,0,0,0,0,0,0,0};
  #pragma unroll
  for (int nt = 0; nt < 2; ++nt) {
    const int c  = (w << 5) + (nt << 4) + l15;
    const float bvx = bx1[c];
    const float bvr = br1[c];
    #pragma unroll
    for (int mt = 0; mt < 2; ++mt) {
      #pragma unroll
      for (int r = 0; r < 4; ++r) {
        const int row = (mt << 4) + (lg << 2) + r;
        const float v = fmaxf(acc1[mt][nt][r] * s + bvx, 0.f);
        _Float16 h, lo2; split16(v, h, lo2);
        const int ad = row * 256 + (c ^ ((row & 7) << 3));
        h1h[ad] = h; h1l[ad] = lo2;
      }
      const int p = (mt << 2) + lg;   // pair index 0..7
      float sm = 0.f;
      #pragma unroll
      for (int r = 0; r < 4; ++r) sm += fmaxf(accm[mt][nt][r] * s + bvr, 0.f);
      h1m[p * 256 + (c ^ ((p & 7) << 3))] = (_Float16)(0.25f * sm * 16.0f);
    }
  }
  __syncthreads();

  // ---------- GEMM2 (attn logits, split) + gate (plain) ----------
  f32x4 acc2[2][2];
  f32x4 acc3[2];
  #pragma unroll
  for (int mt = 0; mt < 2; ++mt) { acc2[mt][0] = (f32x4){0,0,0,0}; acc2[mt][1] = (f32x4){0,0,0,0}; }
  acc3[0] = (f32x4){0,0,0,0}; acc3[1] = (f32x4){0,0,0,0};
  {
    f16x8 wh[3][2], wl[3][2], wg[3][2];
    f16x8 a2h[2][2], a2l[2][2], am[2];
    #pragma unroll
    for (int p = 0; p < 2; ++p)
      #pragma unroll
      for (int nt = 0; nt < 2; ++nt) {
        const int fb = (((ct0 + nt) << 3) + p) * 512 + l * 8;
        wh[p][nt] = *(const f16x8*)(ws + O_W2X_H + fb);
        wl[p][nt] = *(const f16x8*)(ws + O_W2X_L + fb);
        wg[p][nt] = *(const f16x8*)(ws + O_W2G_H + fb);
      }
    #pragma unroll
    for (int mt = 0; mt < 2; ++mt) {
      const int row = (mt << 4) + l15;
      const int ad  = row * 256 + ((lg << 3) ^ ((row & 7) << 3));
      a2h[0][mt] = *(const f16x8*)(h1h + ad);
      a2l[0][mt] = *(const f16x8*)(h1l + ad);
    }
    am[0] = *(const f16x8*)(h1m + l15 * 256 + ((lg << 3) ^ ((l15 & 7) << 3)));
    #pragma unroll
    for (int kk = 0; kk < 8; ++kk) {
      const int cs = kk % 3, ns = (kk + 2) % 3, ab = kk & 1, an = ab ^ 1;
      if (kk < 6) {
        #pragma unroll
        for (int nt = 0; nt < 2; ++nt) {
          const int fb = (((ct0 + nt) << 3) + (kk + 2)) * 512 + l * 8;
          wh[ns][nt] = *(const f16x8*)(ws + O_W2X_H + fb);
          wl[ns][nt] = *(const f16x8*)(ws + O_W2X_L + fb);
          wg[ns][nt] = *(const f16x8*)(ws + O_W2G_H + fb);
        }
      }
      if (kk < 7) {
        #pragma unroll
        for (int mt = 0; mt < 2; ++mt) {
          const int row = (mt << 4) + l15;
          const int ad  = row * 256 + ((((kk + 1) << 5) + (lg << 3)) ^ ((row & 7) << 3));
          a2h[an][mt] = *(const f16x8*)(h1h + ad);
          a2l[an][mt] = *(const f16x8*)(h1l + ad);
        }
        am[an] = *(const f16x8*)(h1m + l15 * 256 + ((((kk + 1) << 5) + (lg << 3)) ^ ((l15 & 7) << 3)));
      }
      #pragma unroll
      for (int nt = 0; nt < 2; ++nt) {
        #pragma unroll
        for (int mt = 0; mt < 2; ++mt) {
          acc2[mt][nt] = MFMA16(a2h[ab][mt], wh[cs][nt], acc2[mt][nt], 0, 0, 0);
          acc2[mt][nt] = MFMA16(a2l[ab][mt], wh[cs][nt], acc2[mt][nt], 0, 0, 0);
          acc2[mt][nt] = MFMA16(a2h[ab][mt], wl[cs][nt], acc2[mt][nt], 0, 0, 0);
        }
        acc3[nt] = MFMA16(am[ab], wg[cs][nt], acc3[nt], 0, 0, 0);
      }
    }
  }

  // ---- softmax over n (in-lane) + circular mean -> axis_out (fp32) ----
  // b_axis2 omitted: constant per column across n, cancels in softmax(axis=0).
  #pragma unroll
  for (int nt = 0; nt < 2; ++nt) {
    const int c = (w << 5) + (nt << 4) + l15;
    #pragma unroll
    for (int mt = 0; mt < 2; ++mt) {
      float lv[4];
      #pragma unroll
      for (int r = 0; r < 4; ++r) lv[r] = acc2[mt][nt][r] * s;
      const float mx = fmaxf(fmaxf(lv[0], lv[1]), fmaxf(lv[2], lv[3]));
      float e[4]; float sum = 0.f;
      #pragma unroll
      for (int r = 0; r < 4; ++r) { e[r] = __expf(lv[r] - mx); sum += e[r]; }
      const float inv = 1.f / sum;
      const int g = g0 + (mt << 2) + lg;
      float x = 0.f, y = 0.f;
      #pragma unroll
      for (int r = 0; r < 4; ++r) {
        const float av = axisF[(r * BH + g) * 256 + c];
        float sn, cs2;
        __sincosf(av, &sn, &cs2);
        const float at = e[r] * inv;
        x += at * cs2;
        y += at * sn;
      }
      if (fabsf(x) < 0.001f) x = 0.001f;
      out[g * 256 + c] = atan2f(y, x);
    }
  }

  // ---- sigmoid gate * min_n arg -> arg_out (fp32) ----
  #pragma unroll
  for (int nt = 0; nt < 2; ++nt) {
    const int c = (w << 5) + (nt << 4) + l15;
    const float bgv = bg2[c];
    #pragma unroll
    for (int r = 0; r < 4; ++r) {
      const int p = (lg << 2) + r;   // gate C row = pair index; only 0..7 live
      if (p < 8) {
        const int g = g0 + p;
        const float gate = 1.f / (1.f + __expf(-(acc3[nt][r] * s + bgv)));
        float mn = argF[g * 256 + c];
        #pragma unroll
        for (int n = 1; n < 4; ++n)
          mn = fminf(mn, argF[(n * BH + g) * 256 + c]);
        out[OUT_ARG_OFF + g * 256 + c] = mn * gate;
      }
    }
  }
}

extern "C" void kernel_launch(void* const* d_in, const int* in_sizes, int n_in,
                              void* d_out, int out_size, void* d_ws, size_t ws_size,
                              hipStream_t stream) {
  const float* axisF = (const float*)d_in[0];
  const float* argF  = (const float*)d_in[1];
  const float* Wx1   = (const float*)d_in[2];
  const float* bx1   = (const float*)d_in[3];
  const float* Wr1   = (const float*)d_in[4];
  const float* br1   = (const float*)d_in[5];
  const float* W2x   = (const float*)d_in[6];
  // d_in[7] = b_axis2: constant over n at fixed column -> cancels in softmax
  const float* W2g   = (const float*)d_in[8];
  const float* bg2   = (const float*)d_in[9];
  float* out = (float*)d_out;
  _Float16* ws = (_Float16*)d_ws;

  combine_weights<<<256, 256, 0, stream>>>(Wx1, Wr1, W2x, W2g, ws);
  cone_main<<<4096, 512, 0, stream>>>(axisF, argF, bx1, br1, bg2, ws, out);
}